// Round 3
// baseline (1541.594 us; speedup 1.0000x reference)
//
#include <hip/hip_runtime.h>

#define HH 56
#define WW 56
#define CC 512
#define BB 32
#define LL (HH*WW)
#define MM (BB*LL)     // 100352 tokens
#define HID 2048

typedef __attribute__((ext_vector_type(8))) __bf16 bf16x8;
typedef __attribute__((ext_vector_type(4))) float f32x4;

__device__ __forceinline__ short f2bf(float f) {
    union { float f; unsigned u; } c; c.f = f;
    unsigned r = c.u + 0x7fffu + ((c.u >> 16) & 1u);   // round-to-nearest-even
    return (short)(r >> 16);
}
__device__ __forceinline__ float bf2f(short s) {
    union { unsigned u; float f; } c; c.u = ((unsigned)(unsigned short)s) << 16;
    return c.f;
}

// ---------------- f32 -> bf16 weight conversion ----------------
__global__ __launch_bounds__(256) void cvt_bf16(const float* __restrict__ in,
                                                short* __restrict__ out, int n) {
    int i = blockIdx.x * 256 + threadIdx.x;
    if (i < n) out[i] = f2bf(in[i]);
}

// ---------------- LayerNorm over 512 channels, 1 row / block ----------------
__global__ __launch_bounds__(256) void ln512(const float* __restrict__ x,
                                             const float* __restrict__ g,
                                             const float* __restrict__ b,
                                             short* __restrict__ out) {
    const int row = blockIdx.x;
    const int t = threadIdx.x;
    const float2 v = ((const float2*)(x + (long)row * 512))[t];
    float s = v.x + v.y;
    float q = v.x * v.x + v.y * v.y;
#pragma unroll
    for (int off = 32; off > 0; off >>= 1) {
        s += __shfl_xor(s, off, 64);
        q += __shfl_xor(q, off, 64);
    }
    __shared__ float red[8];
    const int wv = t >> 6;
    if ((t & 63) == 0) { red[wv] = s; red[4 + wv] = q; }
    __syncthreads();
    s = red[0] + red[1] + red[2] + red[3];
    q = red[4] + red[5] + red[6] + red[7];
    const float mu = s * (1.0f / 512.0f);
    const float rs = rsqrtf(q * (1.0f / 512.0f) - mu * mu + 1e-5f);
    const float2 gv = ((const float2*)g)[t];
    const float2 bv = ((const float2*)b)[t];
    const float y0 = (v.x - mu) * rs * gv.x + bv.x;
    const float y1 = (v.y - mu) * rs * gv.y + bv.y;
    union { short s2[2]; unsigned u; } o;
    o.s2[0] = f2bf(y0); o.s2[1] = f2bf(y1);
    ((unsigned*)out)[(long)row * 256 + t] = o.u;
}

// ---------------- spatial (window) MLP + residual ----------------
__global__ __launch_bounds__(256) void spatial_mlp(const short* __restrict__ xn,
                                                   const float* __restrict__ x,
                                                   const float* __restrict__ sw,
                                                   const float* __restrict__ sb,
                                                   float* x1) {
    const int head = blockIdx.y;
    const int t = threadIdx.x;
    const int ch = t & 31;
    const int wloc = t >> 5;
    const int win = blockIdx.x * 8 + wloc;        // 0..2591
    const int b = win / 81;
    const int rr = win - b * 81;
    const int wi = rr / 9;
    const int wj = rr - wi * 9;
    const int c = head * 32 + ch;

    float xv[49];
#pragma unroll
    for (int j = 0; j < 49; j++) {
        const int pr = wi * 7 + j / 7 - 4;        // padded row - P_T
        const int pc = wj * 7 + j % 7 - 4;        // padded col - P_L
        float v = 0.0f;
        if (pr >= 0 && pr < 56 && pc >= 0 && pc < 56)
            v = bf2f(xn[((long)((b * 56 + pr) * 56 + pc)) * 512 + c]);
        xv[j] = v;
    }

    const float* swh = sw + head * 2401;
    const float* sbh = sb + head * 49;

#pragma unroll 1
    for (int t7 = 0; t7 < 7; t7++) {
        float acc[7];
#pragma unroll
        for (int ii = 0; ii < 7; ii++) acc[ii] = sbh[t7 * 7 + ii];
#pragma unroll
        for (int ii = 0; ii < 7; ii++) {
            const float* swr = swh + (t7 * 7 + ii) * 49;
#pragma unroll
            for (int j = 0; j < 49; j++)
                acc[ii] = fmaf(swr[j], xv[j], acc[ii]);
        }
        const int pr = wi * 7 + t7 - 4;
        if (pr >= 0 && pr < 56) {
#pragma unroll
            for (int ii = 0; ii < 7; ii++) {
                const int pc = wj * 7 + ii - 4;
                if (pc >= 0 && pc < 56) {
                    const long idx = ((long)((b * 56 + pr) * 56 + pc)) * 512 + c;
                    x1[idx] = x[idx] + acc[ii];
                }
            }
        }
    }
}

// ---------------- 256x256 8-wave deep-pipelined bf16 GEMM --------------------
// A[M,K] row-major, Bw[N,K] row-major (B^T). BK=32, 4-deep LDS ring (128 KB),
// 2 phases per K-tile: {ds_read frags, stage 2x global_load_lds, barrier,
// lgkmcnt(0), setprio(1), 16 MFMA, setprio(0), barrier}. Counted vmcnt(8)
// at tile boundary only (3 tiles in flight); tail peels vmcnt(4)/vmcnt(0).
// Staging targets buf[(t+3)&3], consumed at tile t-1's end barrier (race-free).
// T2 swizzle: 16B chunk ^= swz(row); write side via pre-swizzled global src.
template <int K, int N, bool GELU>
__global__ __launch_bounds__(512, 2) void gemm256(const short* __restrict__ A,
                                                  const short* __restrict__ Bw,
                                                  const float* __restrict__ bias,
                                                  const float* res,
                                                  void* Cout) {
    __shared__ __attribute__((aligned(16))) short S[65536];   // 128 KB: A bufs @0, B bufs @64KB
    const int tid = threadIdx.x;
    const int lane = tid & 63;
    const int wid = tid >> 6;
    const int wr = wid >> 2;          // 0..1  M-half (128 rows)
    const int wc = wid & 3;           // 0..3  N-quarter (64 cols)
    const int lr = lane & 15;
    const int kg = (lane >> 4) & 3;
    const long mBase = (long)blockIdx.y * 256;
    const long nBase = (long)blockIdx.x * 256;

    // staging source (per-thread, fixed): pre-swizzled column chunk
    const int sRow = tid >> 2;                       // 0..127 within 8KB round
    const int sChunk = (tid & 3) ^ ((tid >> 3) & 3); // XOR swizzle (write side)
    const short* aSrc0 = A + (mBase + sRow) * K + sChunk * 8;
    const short* aSrc1 = A + (mBase + 128 + sRow) * K + sChunk * 8;
    const short* bSrc0 = Bw + (nBase + sRow) * K + sChunk * 8;
    const short* bSrc1 = Bw + (nBase + 128 + sRow) * K + sChunk * 8;

    auto stageA = [&](int t) {
        const int b = t & 3;
        const long k0 = (long)t * 32;
        __builtin_amdgcn_global_load_lds(
            (const __attribute__((address_space(1))) void*)(aSrc0 + k0),
            (__attribute__((address_space(3))) void*)((char*)S + b * 16384 + wid * 1024),
            16, 0, 0);
        __builtin_amdgcn_global_load_lds(
            (const __attribute__((address_space(1))) void*)(aSrc1 + k0),
            (__attribute__((address_space(3))) void*)((char*)S + b * 16384 + 8192 + wid * 1024),
            16, 0, 0);
    };
    auto stageB = [&](int t) {
        const int b = t & 3;
        const long k0 = (long)t * 32;
        __builtin_amdgcn_global_load_lds(
            (const __attribute__((address_space(1))) void*)(bSrc0 + k0),
            (__attribute__((address_space(3))) void*)((char*)S + 65536 + b * 16384 + wid * 1024),
            16, 0, 0);
        __builtin_amdgcn_global_load_lds(
            (const __attribute__((address_space(1))) void*)(bSrc1 + k0),
            (__attribute__((address_space(3))) void*)((char*)S + 65536 + b * 16384 + 8192 + wid * 1024),
            16, 0, 0);
    };

    // fragment LDS byte offsets (row*64 + swizzled-chunk*16); swz = (lr>>1)&3
    const int swzc = kg ^ ((lr >> 1) & 3);
    const int aOff = (wr * 128 + lr) * 64 + swzc * 16;   // + m*1024
    const int bOff = (wc * 64 + lr) * 64 + swzc * 16;    // + n*1024

    f32x4 acc[8][4] = {};

    stageA(0); stageB(0); stageA(1); stageB(1); stageA(2); stageB(2);
    asm volatile("s_waitcnt vmcnt(8)" ::: "memory");     // tile 0 landed (8 left)
    __builtin_amdgcn_s_barrier();

    const int NT = K / 32;
    for (int t = 0; t < NT; ++t) {
        const char* Ab = (const char*)S + (t & 3) * 16384;
        const char* Bb = (const char*)S + 65536 + (t & 3) * 16384;
        bf16x8 af[4], bf[4];

        // ---- phase A: quadrants m0-3 ----
#pragma unroll
        for (int m = 0; m < 4; ++m) af[m] = *(const bf16x8*)(Ab + aOff + m * 1024);
#pragma unroll
        for (int n = 0; n < 4; ++n) bf[n] = *(const bf16x8*)(Bb + bOff + n * 1024);
        if (t + 3 < NT) stageA(t + 3);
        __builtin_amdgcn_s_barrier();
        asm volatile("s_waitcnt lgkmcnt(0)" ::: "memory");
        __builtin_amdgcn_sched_barrier(0);
        __builtin_amdgcn_s_setprio(1);
#pragma unroll
        for (int m = 0; m < 4; ++m)
#pragma unroll
            for (int n = 0; n < 4; ++n)
                acc[m][n] = __builtin_amdgcn_mfma_f32_16x16x32_bf16(af[m], bf[n],
                                                                    acc[m][n], 0, 0, 0);
        __builtin_amdgcn_s_setprio(0);
        __builtin_amdgcn_s_barrier();

        // ---- phase B: quadrants m4-7 (B frags reused in regs) ----
#pragma unroll
        for (int m = 0; m < 4; ++m) af[m] = *(const bf16x8*)(Ab + aOff + (4 + m) * 1024);
        if (t + 3 < NT) stageB(t + 3);
        __builtin_amdgcn_s_barrier();
        asm volatile("s_waitcnt lgkmcnt(0)" ::: "memory");
        __builtin_amdgcn_sched_barrier(0);
        __builtin_amdgcn_s_setprio(1);
#pragma unroll
        for (int m = 0; m < 4; ++m)
#pragma unroll
            for (int n = 0; n < 4; ++n)
                acc[4 + m][n] = __builtin_amdgcn_mfma_f32_16x16x32_bf16(af[m], bf[n],
                                                                        acc[4 + m][n], 0, 0, 0);
        __builtin_amdgcn_s_setprio(0);
        // tile boundary: wait next tile's stages (counted; drains only at tail)
        if (t + 1 < NT) {
            if (t < NT - 3)       asm volatile("s_waitcnt vmcnt(8)" ::: "memory");
            else if (t == NT - 3) asm volatile("s_waitcnt vmcnt(4)" ::: "memory");
            else                  asm volatile("s_waitcnt vmcnt(0)" ::: "memory");
        }
        __builtin_amdgcn_s_barrier();
    }

    // epilogue: C/D 16x16 layout col = lane&15, row = (lane>>4)*4 + reg
#pragma unroll
    for (int n = 0; n < 4; ++n) {
        const long col = nBase + wc * 64 + n * 16 + lr;
        const float bv = bias[col];
#pragma unroll
        for (int m = 0; m < 8; ++m) {
#pragma unroll
            for (int r = 0; r < 4; ++r) {
                const long row = mBase + wr * 128 + m * 16 + kg * 4 + r;
                float v = acc[m][n][r] + bv;
                const long idx = row * N + col;
                if (GELU) {
                    v = 0.5f * v * (1.0f + erff(v * 0.70710678118f));
                    ((short*)Cout)[idx] = f2bf(v);
                } else {
                    ((float*)Cout)[idx] = res[idx] + v;
                }
            }
        }
    }
}

extern "C" void kernel_launch(void* const* d_in, const int* in_sizes, int n_in,
                              void* d_out, int out_size, void* d_ws, size_t ws_size,
                              hipStream_t stream) {
    const float* x    = (const float*)d_in[0];
    const float* n1g  = (const float*)d_in[1];
    const float* n1b  = (const float*)d_in[2];
    const float* sw   = (const float*)d_in[3];
    const float* sb   = (const float*)d_in[4];
    const float* n2g  = (const float*)d_in[5];
    const float* n2b  = (const float*)d_in[6];
    const float* fc1w = (const float*)d_in[7];
    const float* fc1b = (const float*)d_in[8];
    const float* fc2w = (const float*)d_in[9];
    const float* fc2b = (const float*)d_in[10];
    float* out = (float*)d_out;

    // workspace layout (bytes)
    char* ws = (char*)d_ws;
    short* xn  = (short*)ws;                      // MM*512*2    = 102,760,448  (xn, then xn2)
    short* hb  = (short*)(ws + 102760448);        // MM*2048*2   = 411,041,792
    short* w1b = (short*)(ws + 513802240);        // 2048*512*2  =   2,097,152
    short* w2b = (short*)(ws + 515899392);        // 512*2048*2  =   2,097,152

    cvt_bf16<<<4096, 256, 0, stream>>>(fc1w, w1b, 2048 * 512);
    cvt_bf16<<<4096, 256, 0, stream>>>(fc2w, w2b, 512 * 2048);

    // LN1: x -> xn (bf16)
    ln512<<<MM, 256, 0, stream>>>(x, n1g, n1b, xn);

    // spatial MLP + residual: x1 = x + y  (into d_out)
    spatial_mlp<<<dim3(324, 16), 256, 0, stream>>>(xn, x, sw, sb, out);

    // LN2: x1 -> xn2 (bf16, reuse xn buffer)
    ln512<<<MM, 256, 0, stream>>>(out, n2g, n2b, xn);

    // FC1 + gelu -> h (bf16)   grid: x = N-strips (8), y = M-strips (392)
    gemm256<512, 2048, true><<<dim3(8, 392), 512, 0, stream>>>(xn, w1b, fc1b, nullptr, hb);

    // FC2 + bias + residual -> out (f32, reads x1 from d_out in place)
    gemm256<2048, 512, false><<<dim3(2, 392), 512, 0, stream>>>(hb, w2b, fc2b, out, out);
}

// Round 4
// 1367.186 us; speedup vs baseline: 1.1276x; 1.1276x over previous
//
#include <hip/hip_runtime.h>

#define HH 56
#define WW 56
#define CC 512
#define BB 32
#define LL (HH*WW)
#define MM (BB*LL)     // 100352 tokens
#define HID 2048

typedef __attribute__((ext_vector_type(8))) __bf16 bf16x8;
typedef __attribute__((ext_vector_type(4))) float f32x4;
typedef __attribute__((ext_vector_type(4))) short s16x4;

__device__ __forceinline__ short f2bf(float f) {
    union { float f; unsigned u; } c; c.f = f;
    unsigned r = c.u + 0x7fffu + ((c.u >> 16) & 1u);   // round-to-nearest-even
    return (short)(r >> 16);
}
__device__ __forceinline__ float bf2f(short s) {
    union { unsigned u; float f; } c; c.u = ((unsigned)(unsigned short)s) << 16;
    return c.f;
}

// ---------------- f32 -> bf16 weight conversion ----------------
__global__ __launch_bounds__(256) void cvt_bf16(const float* __restrict__ in,
                                                short* __restrict__ out, int n) {
    int i = blockIdx.x * 256 + threadIdx.x;
    if (i < n) out[i] = f2bf(in[i]);
}

// ---------------- LayerNorm over 512 channels, 1 row / block ----------------
__global__ __launch_bounds__(256) void ln512(const float* __restrict__ x,
                                             const float* __restrict__ g,
                                             const float* __restrict__ b,
                                             short* __restrict__ out) {
    const int row = blockIdx.x;
    const int t = threadIdx.x;
    const float2 v = ((const float2*)(x + (long)row * 512))[t];
    float s = v.x + v.y;
    float q = v.x * v.x + v.y * v.y;
#pragma unroll
    for (int off = 32; off > 0; off >>= 1) {
        s += __shfl_xor(s, off, 64);
        q += __shfl_xor(q, off, 64);
    }
    __shared__ float red[8];
    const int wv = t >> 6;
    if ((t & 63) == 0) { red[wv] = s; red[4 + wv] = q; }
    __syncthreads();
    s = red[0] + red[1] + red[2] + red[3];
    q = red[4] + red[5] + red[6] + red[7];
    const float mu = s * (1.0f / 512.0f);
    const float rs = rsqrtf(q * (1.0f / 512.0f) - mu * mu + 1e-5f);
    const float2 gv = ((const float2*)g)[t];
    const float2 bv = ((const float2*)b)[t];
    const float y0 = (v.x - mu) * rs * gv.x + bv.x;
    const float y1 = (v.y - mu) * rs * gv.y + bv.y;
    union { short s2[2]; unsigned u; } o;
    o.s2[0] = f2bf(y0); o.s2[1] = f2bf(y1);
    ((unsigned*)out)[(long)row * 256 + t] = o.u;
}

// ---------------- spatial (window) MLP + residual ----------------
__global__ __launch_bounds__(256) void spatial_mlp(const short* __restrict__ xn,
                                                   const float* __restrict__ x,
                                                   const float* __restrict__ sw,
                                                   const float* __restrict__ sb,
                                                   float* x1) {
    const int head = blockIdx.y;
    const int t = threadIdx.x;
    const int ch = t & 31;
    const int wloc = t >> 5;
    const int win = blockIdx.x * 8 + wloc;        // 0..2591
    const int b = win / 81;
    const int rr = win - b * 81;
    const int wi = rr / 9;
    const int wj = rr - wi * 9;
    const int c = head * 32 + ch;

    float xv[49];
#pragma unroll
    for (int j = 0; j < 49; j++) {
        const int pr = wi * 7 + j / 7 - 4;        // padded row - P_T
        const int pc = wj * 7 + j % 7 - 4;        // padded col - P_L
        float v = 0.0f;
        if (pr >= 0 && pr < 56 && pc >= 0 && pc < 56)
            v = bf2f(xn[((long)((b * 56 + pr) * 56 + pc)) * 512 + c]);
        xv[j] = v;
    }

    const float* swh = sw + head * 2401;
    const float* sbh = sb + head * 49;

#pragma unroll 1
    for (int t7 = 0; t7 < 7; t7++) {
        float acc[7];
#pragma unroll
        for (int ii = 0; ii < 7; ii++) acc[ii] = sbh[t7 * 7 + ii];
#pragma unroll
        for (int ii = 0; ii < 7; ii++) {
            const float* swr = swh + (t7 * 7 + ii) * 49;
#pragma unroll
            for (int j = 0; j < 49; j++)
                acc[ii] = fmaf(swr[j], xv[j], acc[ii]);
        }
        const int pr = wi * 7 + t7 - 4;
        if (pr >= 0 && pr < 56) {
#pragma unroll
            for (int ii = 0; ii < 7; ii++) {
                const int pc = wj * 7 + ii - 4;
                if (pc >= 0 && pc < 56) {
                    const long idx = ((long)((b * 56 + pr) * 56 + pc)) * 512 + c;
                    x1[idx] = x[idx] + acc[ii];
                }
            }
        }
    }
}

// ---------------- 256x256 8-wave deep-pipelined bf16 GEMM --------------------
// A[M,K] row-major, Bw[N,K] row-major (B^T). BK=32, 4-deep LDS ring (128 KB).
// Per K-tile, 2 phases: {ds_read frags; stage half-tile; barrier; lgkmcnt(0);
// setprio(1); 16 MFMA; setprio(0); barrier}. NO sched_barrier (m141: walls
// defeat compiler scheduling). Counted vmcnt(8) at tile boundary only.
// MFMA operand-swapped (computes C^T fragment): lane holds 4 consecutive
// N-elements of one C-row -> vectorized 16B/8B epilogue stores.
// T1 XCD swizzle on block ids (nwg % 8 == 0).
template <int K, int N, bool GELU>
__global__ __launch_bounds__(512, 2) void gemm256(const short* __restrict__ A,
                                                  const short* __restrict__ Bw,
                                                  const float* __restrict__ bias,
                                                  const float* res,
                                                  void* Cout) {
    __shared__ __attribute__((aligned(16))) short S[65536];   // 128 KB
    const int tid = threadIdx.x;
    const int lane = tid & 63;
    const int wid = tid >> 6;
    const int wr = wid >> 2;          // 0..1  M-half (128 rows)
    const int wc = wid & 3;           // 0..3  N-quarter (64 cols)
    const int lr = lane & 15;
    const int kg = (lane >> 4) & 3;

    // T1: bijective XCD-aware remap — consecutive origs (same M-row strip set)
    // land on one XCD.
    const int gx = gridDim.x;
    const int lin = blockIdx.y * gx + blockIdx.x;
    const int cpx = (gx * gridDim.y) >> 3;
    const int orig = (lin & 7) * cpx + (lin >> 3);
    const long mBase = (long)(orig / gx) * 256;
    const long nBase = (long)(orig % gx) * 256;

    // staging source (per-thread, fixed): pre-swizzled column chunk
    const int sRow = tid >> 2;                       // 0..127 within 8KB round
    const int sChunk = (tid & 3) ^ ((tid >> 3) & 3); // XOR key = (row>>1)&3
    const short* aSrc0 = A + (mBase + sRow) * K + sChunk * 8;
    const short* aSrc1 = A + (mBase + 128 + sRow) * K + sChunk * 8;
    const short* bSrc0 = Bw + (nBase + sRow) * K + sChunk * 8;
    const short* bSrc1 = Bw + (nBase + 128 + sRow) * K + sChunk * 8;

    auto stageA = [&](int t) {
        const int b = t & 3;
        const long k0 = (long)t * 32;
        __builtin_amdgcn_global_load_lds(
            (const __attribute__((address_space(1))) void*)(aSrc0 + k0),
            (__attribute__((address_space(3))) void*)((char*)S + b * 16384 + wid * 1024),
            16, 0, 0);
        __builtin_amdgcn_global_load_lds(
            (const __attribute__((address_space(1))) void*)(aSrc1 + k0),
            (__attribute__((address_space(3))) void*)((char*)S + b * 16384 + 8192 + wid * 1024),
            16, 0, 0);
    };
    auto stageB = [&](int t) {
        const int b = t & 3;
        const long k0 = (long)t * 32;
        __builtin_amdgcn_global_load_lds(
            (const __attribute__((address_space(1))) void*)(bSrc0 + k0),
            (__attribute__((address_space(3))) void*)((char*)S + 65536 + b * 16384 + wid * 1024),
            16, 0, 0);
        __builtin_amdgcn_global_load_lds(
            (const __attribute__((address_space(1))) void*)(bSrc1 + k0),
            (__attribute__((address_space(3))) void*)((char*)S + 65536 + b * 16384 + 8192 + wid * 1024),
            16, 0, 0);
    };

    // fragment LDS byte offsets (row*64 + swizzled-chunk*16); key = (row>>1)&3
    const int swzc = kg ^ ((lr >> 1) & 3);
    const int aOff = (wr * 128 + lr) * 64 + swzc * 16;   // + m*1024
    const int bOff = (wc * 64 + lr) * 64 + swzc * 16;    // + n*1024

    f32x4 acc[8][4] = {};

    stageA(0); stageB(0); stageA(1); stageB(1); stageA(2); stageB(2);
    asm volatile("s_waitcnt vmcnt(8)" ::: "memory");     // tile 0 landed
    __builtin_amdgcn_s_barrier();

    const int NT = K / 32;
    for (int t = 0; t < NT; ++t) {
        const char* Ab = (const char*)S + (t & 3) * 16384;
        const char* Bb = (const char*)S + 65536 + (t & 3) * 16384;
        bf16x8 af[4], bf[4];

        // ---- phase A: quadrants m0-3 ----
#pragma unroll
        for (int m = 0; m < 4; ++m) af[m] = *(const bf16x8*)(Ab + aOff + m * 1024);
#pragma unroll
        for (int n = 0; n < 4; ++n) bf[n] = *(const bf16x8*)(Bb + bOff + n * 1024);
        if (t + 3 < NT) stageA(t + 3);
        __builtin_amdgcn_s_barrier();
        asm volatile("s_waitcnt lgkmcnt(0)" ::: "memory");
        __builtin_amdgcn_s_setprio(1);
#pragma unroll
        for (int m = 0; m < 4; ++m)
#pragma unroll
            for (int n = 0; n < 4; ++n)
                acc[m][n] = __builtin_amdgcn_mfma_f32_16x16x32_bf16(bf[n], af[m],
                                                                    acc[m][n], 0, 0, 0);
        __builtin_amdgcn_s_setprio(0);
        __builtin_amdgcn_s_barrier();

        // ---- phase B: quadrants m4-7 (B frags reused in regs) ----
#pragma unroll
        for (int m = 0; m < 4; ++m) af[m] = *(const bf16x8*)(Ab + aOff + (4 + m) * 1024);
        if (t + 3 < NT) stageB(t + 3);
        __builtin_amdgcn_s_barrier();
        asm volatile("s_waitcnt lgkmcnt(0)" ::: "memory");
        __builtin_amdgcn_s_setprio(1);
#pragma unroll
        for (int m = 0; m < 4; ++m)
#pragma unroll
            for (int n = 0; n < 4; ++n)
                acc[4 + m][n] = __builtin_amdgcn_mfma_f32_16x16x32_bf16(bf[n], af[m],
                                                                        acc[4 + m][n], 0, 0, 0);
        __builtin_amdgcn_s_setprio(0);
        // tile boundary: counted vmcnt (drains only at tail)
        if (t + 1 < NT) {
            if (t < NT - 3)       asm volatile("s_waitcnt vmcnt(8)" ::: "memory");
            else if (t == NT - 3) asm volatile("s_waitcnt vmcnt(4)" ::: "memory");
            else                  asm volatile("s_waitcnt vmcnt(0)" ::: "memory");
        }
        __builtin_amdgcn_s_barrier();
    }

    // epilogue: operand-swapped fragment = C^T layout:
    //   C row  = mBase + wr*128 + m*16 + lr
    //   C cols = nBase + wc*64 + n*16 + kg*4 + (0..3)   (consecutive!)
#pragma unroll
    for (int n = 0; n < 4; ++n) {
        const long col0 = nBase + wc * 64 + n * 16 + kg * 4;
        const f32x4 bv4 = *(const f32x4*)(bias + col0);
#pragma unroll
        for (int m = 0; m < 8; ++m) {
            const long row = mBase + wr * 128 + m * 16 + lr;
            const long idx = row * N + col0;
            if (GELU) {
                s16x4 o;
#pragma unroll
                for (int r = 0; r < 4; ++r) {
                    float v = acc[m][n][r] + bv4[r];
                    v = 0.5f * v * (1.0f + erff(v * 0.70710678118f));
                    o[r] = f2bf(v);
                }
                *(s16x4*)((short*)Cout + idx) = o;
            } else {
                const f32x4 rv = *(const f32x4*)(res + idx);
                f32x4 o;
#pragma unroll
                for (int r = 0; r < 4; ++r) o[r] = acc[m][n][r] + bv4[r] + rv[r];
                *(f32x4*)((float*)Cout + idx) = o;
            }
        }
    }
}

extern "C" void kernel_launch(void* const* d_in, const int* in_sizes, int n_in,
                              void* d_out, int out_size, void* d_ws, size_t ws_size,
                              hipStream_t stream) {
    const float* x    = (const float*)d_in[0];
    const float* n1g  = (const float*)d_in[1];
    const float* n1b  = (const float*)d_in[2];
    const float* sw   = (const float*)d_in[3];
    const float* sb   = (const float*)d_in[4];
    const float* n2g  = (const float*)d_in[5];
    const float* n2b  = (const float*)d_in[6];
    const float* fc1w = (const float*)d_in[7];
    const float* fc1b = (const float*)d_in[8];
    const float* fc2w = (const float*)d_in[9];
    const float* fc2b = (const float*)d_in[10];
    float* out = (float*)d_out;

    // workspace layout (bytes)
    char* ws = (char*)d_ws;
    short* xn  = (short*)ws;                      // MM*512*2    = 102,760,448  (xn, then xn2)
    short* hb  = (short*)(ws + 102760448);        // MM*2048*2   = 411,041,792
    short* w1b = (short*)(ws + 513802240);        // 2048*512*2  =   2,097,152
    short* w2b = (short*)(ws + 515899392);        // 512*2048*2  =   2,097,152

    cvt_bf16<<<4096, 256, 0, stream>>>(fc1w, w1b, 2048 * 512);
    cvt_bf16<<<4096, 256, 0, stream>>>(fc2w, w2b, 512 * 2048);

    // LN1: x -> xn (bf16)
    ln512<<<MM, 256, 0, stream>>>(x, n1g, n1b, xn);

    // spatial MLP + residual: x1 = x + y  (into d_out)
    spatial_mlp<<<dim3(324, 16), 256, 0, stream>>>(xn, x, sw, sb, out);

    // LN2: x1 -> xn2 (bf16, reuse xn buffer)
    ln512<<<MM, 256, 0, stream>>>(out, n2g, n2b, xn);

    // FC1 + gelu -> h (bf16)   grid: x = N-strips (8), y = M-strips (392)
    gemm256<512, 2048, true><<<dim3(8, 392), 512, 0, stream>>>(xn, w1b, fc1b, nullptr, hb);

    // FC2 + bias + residual -> out (f32, reads x1 from d_out in place)
    gemm256<2048, 512, false><<<dim3(2, 392), 512, 0, stream>>>(hb, w2b, fc2b, out, out);
}

// Round 5
// 1203.887 us; speedup vs baseline: 1.2805x; 1.1356x over previous
//
#include <hip/hip_runtime.h>

#define HH 56
#define WW 56
#define CC 512
#define BB 32
#define LL (HH*WW)
#define MM (BB*LL)     // 100352 tokens
#define HID 2048

typedef __attribute__((ext_vector_type(8))) __bf16 bf16x8;
typedef __attribute__((ext_vector_type(4))) float f32x4;
typedef __attribute__((ext_vector_type(4))) short s16x4;

__device__ __forceinline__ short f2bf(float f) {
    union { float f; unsigned u; } c; c.f = f;
    unsigned r = c.u + 0x7fffu + ((c.u >> 16) & 1u);   // round-to-nearest-even
    return (short)(r >> 16);
}
__device__ __forceinline__ float bf2f(short s) {
    union { unsigned u; float f; } c; c.u = ((unsigned)(unsigned short)s) << 16;
    return c.f;
}

// fast gelu: v * t/(t+1), t = e^{2*0.7978845608*(v+0.044715 v^3)}
// max abs err vs exact erf-gelu ~3e-4 (<< bf16 ulp of outputs)
__device__ __forceinline__ float gelu_fast(float v) {
    float xg = 0.7978845608f * (v + 0.044715f * v * v * v);
    xg = fminf(xg, 15.0f);                 // avoid inf/inf for huge v
    float t = __expf(2.0f * xg);
    return v * (t / (t + 1.0f));
}

// ---------------- f32 -> bf16 weight conversion ----------------
__global__ __launch_bounds__(256) void cvt_bf16(const float* __restrict__ in,
                                                short* __restrict__ out, int n) {
    int i = blockIdx.x * 256 + threadIdx.x;
    if (i < n) out[i] = f2bf(in[i]);
}

// ---------------- LayerNorm over 512 channels, 1 row / block ----------------
__global__ __launch_bounds__(256) void ln512(const float* __restrict__ x,
                                             const float* __restrict__ g,
                                             const float* __restrict__ b,
                                             short* __restrict__ out) {
    const int row = blockIdx.x;
    const int t = threadIdx.x;
    const float2 v = ((const float2*)(x + (long)row * 512))[t];
    float s = v.x + v.y;
    float q = v.x * v.x + v.y * v.y;
#pragma unroll
    for (int off = 32; off > 0; off >>= 1) {
        s += __shfl_xor(s, off, 64);
        q += __shfl_xor(q, off, 64);
    }
    __shared__ float red[8];
    const int wv = t >> 6;
    if ((t & 63) == 0) { red[wv] = s; red[4 + wv] = q; }
    __syncthreads();
    s = red[0] + red[1] + red[2] + red[3];
    q = red[4] + red[5] + red[6] + red[7];
    const float mu = s * (1.0f / 512.0f);
    const float rs = rsqrtf(q * (1.0f / 512.0f) - mu * mu + 1e-5f);
    const float2 gv = ((const float2*)g)[t];
    const float2 bv = ((const float2*)b)[t];
    const float y0 = (v.x - mu) * rs * gv.x + bv.x;
    const float y1 = (v.y - mu) * rs * gv.y + bv.y;
    union { short s2[2]; unsigned u; } o;
    o.s2[0] = f2bf(y0); o.s2[1] = f2bf(y1);
    ((unsigned*)out)[(long)row * 256 + t] = o.u;
}

// ---------------- spatial (window) MLP + residual ----------------
__global__ __launch_bounds__(256) void spatial_mlp(const short* __restrict__ xn,
                                                   const float* __restrict__ x,
                                                   const float* __restrict__ sw,
                                                   const float* __restrict__ sb,
                                                   float* x1) {
    const int head = blockIdx.y;
    const int t = threadIdx.x;
    const int ch = t & 31;
    const int wloc = t >> 5;
    const int win = blockIdx.x * 8 + wloc;        // 0..2591
    const int b = win / 81;
    const int rr = win - b * 81;
    const int wi = rr / 9;
    const int wj = rr - wi * 9;
    const int c = head * 32 + ch;

    float xv[49];
#pragma unroll
    for (int j = 0; j < 49; j++) {
        const int pr = wi * 7 + j / 7 - 4;        // padded row - P_T
        const int pc = wj * 7 + j % 7 - 4;        // padded col - P_L
        float v = 0.0f;
        if (pr >= 0 && pr < 56 && pc >= 0 && pc < 56)
            v = bf2f(xn[((long)((b * 56 + pr) * 56 + pc)) * 512 + c]);
        xv[j] = v;
    }

    const float* swh = sw + head * 2401;
    const float* sbh = sb + head * 49;

#pragma unroll 1
    for (int t7 = 0; t7 < 7; t7++) {
        float acc[7];
#pragma unroll
        for (int ii = 0; ii < 7; ii++) acc[ii] = sbh[t7 * 7 + ii];
#pragma unroll
        for (int ii = 0; ii < 7; ii++) {
            const float* swr = swh + (t7 * 7 + ii) * 49;
#pragma unroll
            for (int j = 0; j < 49; j++)
                acc[ii] = fmaf(swr[j], xv[j], acc[ii]);
        }
        const int pr = wi * 7 + t7 - 4;
        if (pr >= 0 && pr < 56) {
#pragma unroll
            for (int ii = 0; ii < 7; ii++) {
                const int pc = wj * 7 + ii - 4;
                if (pc >= 0 && pc < 56) {
                    const long idx = ((long)((b * 56 + pr) * 56 + pc)) * 512 + c;
                    x1[idx] = x[idx] + acc[ii];
                }
            }
        }
    }
}

// ---------------- 128x128 4-wave bf16 GEMM, ring-3 counted-vmcnt -------------
// A[M,K] row-major, Bw[N,K] row-major (B^T). BK=32. LDS ring of 3 tile-bufs
// (48 KB total -> 3 blocks/CU = 3 waves/SIMD). Per K-tile (ONE raw s_barrier):
//   stage(t+2) [4 gload_lds]; ds_read 8x b128 from buf[t%3]; lgkmcnt(0);
//   setprio(1); 16 MFMA; setprio(0); vmcnt(4); s_barrier.
// Counted vmcnt(4): next tile's 4 loads complete, t+2's stay in flight.
// T2 XOR swizzle both sides (verified 0 conflicts). MFMA operand-swapped ->
// lane holds 4 consecutive N-cols -> vectorized 16B/8B epilogue stores.
// T1 bijective XCD swizzle (nwg % 8 == 0).
template <int K, int N, bool GELU>
__global__ __launch_bounds__(256, 3) void gemm128(const short* __restrict__ A,
                                                  const short* __restrict__ Bw,
                                                  const float* __restrict__ bias,
                                                  const float* res,
                                                  void* Cout) {
    __shared__ __attribute__((aligned(16))) short S[24576];  // 48 KB: A@0, B@24KB
    const int tid = threadIdx.x;
    const int lane = tid & 63;
    const int wid = tid >> 6;
    const int wr = wid >> 1;          // 0..1  M-half (64 rows)
    const int wc = wid & 1;           // 0..1  N-half (64 cols)
    const int lr = lane & 15;
    const int kg = (lane >> 4) & 3;

    // T1: bijective XCD-aware remap (nwg % 8 == 0)
    const int gx = gridDim.x;
    const int lin = blockIdx.y * gx + blockIdx.x;
    const int cpx = (gx * gridDim.y) >> 3;
    const int orig = (lin & 7) * cpx + (lin >> 3);
    const long mBase = (long)(orig / gx) * 128;
    const long nBase = (long)(orig % gx) * 128;

    // staging source (per-thread, fixed): pre-swizzled K-chunk.
    // LDS dest is linear: rows 0..63 at byte tid*16, rows 64..127 at 4096+tid*16.
    const int sRow = tid >> 2;                        // 0..63
    const int sChunk = (tid & 3) ^ ((tid >> 3) & 3);  // key = (row>>1)&3
    const short* aSrc0 = A + (mBase + sRow) * K + sChunk * 8;
    const short* aSrc1 = A + (mBase + 64 + sRow) * K + sChunk * 8;
    const short* bSrc0 = Bw + (nBase + sRow) * K + sChunk * 8;
    const short* bSrc1 = Bw + (nBase + 64 + sRow) * K + sChunk * 8;

    auto stage = [&](int buf, int t) {
        const long k0 = (long)t * 32;
        char* Ad = (char*)S + buf * 8192 + tid * 16;
        char* Bd = (char*)S + 24576 + buf * 8192 + tid * 16;
        __builtin_amdgcn_global_load_lds(
            (const __attribute__((address_space(1))) void*)(aSrc0 + k0),
            (__attribute__((address_space(3))) void*)Ad, 16, 0, 0);
        __builtin_amdgcn_global_load_lds(
            (const __attribute__((address_space(1))) void*)(aSrc1 + k0),
            (__attribute__((address_space(3))) void*)(Ad + 4096), 16, 0, 0);
        __builtin_amdgcn_global_load_lds(
            (const __attribute__((address_space(1))) void*)(bSrc0 + k0),
            (__attribute__((address_space(3))) void*)Bd, 16, 0, 0);
        __builtin_amdgcn_global_load_lds(
            (const __attribute__((address_space(1))) void*)(bSrc1 + k0),
            (__attribute__((address_space(3))) void*)(Bd + 4096), 16, 0, 0);
    };

    // fragment LDS byte offsets: row*64 + swizzled-chunk*16, key=(row>>1)&3
    const int swzc = kg ^ ((lr >> 1) & 3);
    const int aOff = (wr * 64 + lr) * 64 + swzc * 16;    // + m*1024, m=0..3
    const int bOff = (wc * 64 + lr) * 64 + swzc * 16;    // + n*1024, n=0..3

    f32x4 acc[4][4] = {};

    stage(0, 0); stage(1, 1);
    asm volatile("s_waitcnt vmcnt(4)" ::: "memory");     // tile 0 landed
    __builtin_amdgcn_s_barrier();

    const int NT = K / 32;
    int cb = 0;                                          // current ring slot
    for (int t = 0; t < NT; ++t) {
        if (t + 2 < NT) {
            const int sb = cb >= 1 ? cb - 1 : 2;         // (cb+2)%3
            stage(sb, t + 2);
        }
        const char* Ab = (const char*)S + cb * 8192;
        const char* Bb = (const char*)S + 24576 + cb * 8192;
        bf16x8 af[4], bf[4];
#pragma unroll
        for (int m = 0; m < 4; ++m) af[m] = *(const bf16x8*)(Ab + aOff + m * 1024);
#pragma unroll
        for (int n = 0; n < 4; ++n) bf[n] = *(const bf16x8*)(Bb + bOff + n * 1024);
        asm volatile("s_waitcnt lgkmcnt(0)" ::: "memory");
        __builtin_amdgcn_s_setprio(1);
#pragma unroll
        for (int m = 0; m < 4; ++m)
#pragma unroll
            for (int n = 0; n < 4; ++n)
                acc[m][n] = __builtin_amdgcn_mfma_f32_16x16x32_bf16(bf[n], af[m],
                                                                    acc[m][n], 0, 0, 0);
        __builtin_amdgcn_s_setprio(0);
        // boundary: buf[t+1] must be landed before next tile reads it
        if (t + 1 < NT) {
            if (t + 2 < NT) asm volatile("s_waitcnt vmcnt(4)" ::: "memory");
            else            asm volatile("s_waitcnt vmcnt(0)" ::: "memory");
        }
        __builtin_amdgcn_s_barrier();
        cb = cb + 1 == 3 ? 0 : cb + 1;
    }

    // epilogue: operand-swapped fragment = C^T layout:
    //   C row  = mBase + wr*64 + m*16 + lr
    //   C cols = nBase + wc*64 + n*16 + kg*4 + (0..3)   (consecutive)
#pragma unroll
    for (int n = 0; n < 4; ++n) {
        const long col0 = nBase + wc * 64 + n * 16 + kg * 4;
        const f32x4 bv4 = *(const f32x4*)(bias + col0);
#pragma unroll
        for (int m = 0; m < 4; ++m) {
            const long row = mBase + wr * 64 + m * 16 + lr;
            const long idx = row * N + col0;
            if (GELU) {
                s16x4 o;
#pragma unroll
                for (int r = 0; r < 4; ++r)
                    o[r] = f2bf(gelu_fast(acc[m][n][r] + bv4[r]));
                *(s16x4*)((short*)Cout + idx) = o;
            } else {
                const f32x4 rv = *(const f32x4*)(res + idx);
                f32x4 o;
#pragma unroll
                for (int r = 0; r < 4; ++r) o[r] = acc[m][n][r] + bv4[r] + rv[r];
                *(f32x4*)((float*)Cout + idx) = o;
            }
        }
    }
}

extern "C" void kernel_launch(void* const* d_in, const int* in_sizes, int n_in,
                              void* d_out, int out_size, void* d_ws, size_t ws_size,
                              hipStream_t stream) {
    const float* x    = (const float*)d_in[0];
    const float* n1g  = (const float*)d_in[1];
    const float* n1b  = (const float*)d_in[2];
    const float* sw   = (const float*)d_in[3];
    const float* sb   = (const float*)d_in[4];
    const float* n2g  = (const float*)d_in[5];
    const float* n2b  = (const float*)d_in[6];
    const float* fc1w = (const float*)d_in[7];
    const float* fc1b = (const float*)d_in[8];
    const float* fc2w = (const float*)d_in[9];
    const float* fc2b = (const float*)d_in[10];
    float* out = (float*)d_out;

    // workspace layout (bytes)
    char* ws = (char*)d_ws;
    short* xn  = (short*)ws;                      // MM*512*2    = 102,760,448  (xn, then xn2)
    short* hb  = (short*)(ws + 102760448);        // MM*2048*2   = 411,041,792
    short* w1b = (short*)(ws + 513802240);        // 2048*512*2  =   2,097,152
    short* w2b = (short*)(ws + 515899392);        // 512*2048*2  =   2,097,152

    cvt_bf16<<<4096, 256, 0, stream>>>(fc1w, w1b, 2048 * 512);
    cvt_bf16<<<4096, 256, 0, stream>>>(fc2w, w2b, 512 * 2048);

    // LN1: x -> xn (bf16)
    ln512<<<MM, 256, 0, stream>>>(x, n1g, n1b, xn);

    // spatial MLP + residual: x1 = x + y  (into d_out)
    spatial_mlp<<<dim3(324, 16), 256, 0, stream>>>(xn, x, sw, sb, out);

    // LN2: x1 -> xn2 (bf16, reuse xn buffer)
    ln512<<<MM, 256, 0, stream>>>(out, n2g, n2b, xn);

    // FC1 + gelu -> h (bf16)   grid: x = 16 N-strips, y = 784 M-strips
    gemm128<512, 2048, true><<<dim3(16, 784), 256, 0, stream>>>(xn, w1b, fc1b, nullptr, hb);

    // FC2 + bias + residual -> out (f32, reads x1 from d_out in place)
    gemm128<2048, 512, false><<<dim3(4, 784), 256, 0, stream>>>(hb, w2b, fc2b, out, out);
}

// Round 6
// 1190.655 us; speedup vs baseline: 1.2947x; 1.0111x over previous
//
#include <hip/hip_runtime.h>

#define HH 56
#define WW 56
#define CC 512
#define BB 32
#define LL (HH*WW)
#define MM (BB*LL)     // 100352 tokens
#define HID 2048

typedef __attribute__((ext_vector_type(8))) __bf16 bf16x8;
typedef __attribute__((ext_vector_type(4))) float f32x4;
typedef __attribute__((ext_vector_type(4))) short s16x4;

__device__ __forceinline__ short f2bf(float f) {
    union { float f; unsigned u; } c; c.f = f;
    unsigned r = c.u + 0x7fffu + ((c.u >> 16) & 1u);   // round-to-nearest-even
    return (short)(r >> 16);
}
__device__ __forceinline__ float bf2f(short s) {
    union { unsigned u; float f; } c; c.u = ((unsigned)(unsigned short)s) << 16;
    return c.f;
}

// fast gelu: v * t/(t+1), t = e^{2*0.7978845608*(v+0.044715 v^3)}
__device__ __forceinline__ float gelu_fast(float v) {
    float xg = 0.7978845608f * (v + 0.044715f * v * v * v);
    xg = fminf(xg, 15.0f);
    float t = __expf(2.0f * xg);
    return v * (t / (t + 1.0f));
}

// ---------------- f32 -> bf16 weight conversion ----------------
__global__ __launch_bounds__(256) void cvt_bf16(const float* __restrict__ in,
                                                short* __restrict__ out, int n) {
    int i = blockIdx.x * 256 + threadIdx.x;
    if (i < n) out[i] = f2bf(in[i]);
}

// ---------------- LayerNorm over 512 channels, 1 row / block ----------------
__global__ __launch_bounds__(256) void ln512(const float* __restrict__ x,
                                             const float* __restrict__ g,
                                             const float* __restrict__ b,
                                             short* __restrict__ out) {
    const int row = blockIdx.x;
    const int t = threadIdx.x;
    const float2 v = ((const float2*)(x + (long)row * 512))[t];
    float s = v.x + v.y;
    float q = v.x * v.x + v.y * v.y;
#pragma unroll
    for (int off = 32; off > 0; off >>= 1) {
        s += __shfl_xor(s, off, 64);
        q += __shfl_xor(q, off, 64);
    }
    __shared__ float red[8];
    const int wv = t >> 6;
    if ((t & 63) == 0) { red[wv] = s; red[4 + wv] = q; }
    __syncthreads();
    s = red[0] + red[1] + red[2] + red[3];
    q = red[4] + red[5] + red[6] + red[7];
    const float mu = s * (1.0f / 512.0f);
    const float rs = rsqrtf(q * (1.0f / 512.0f) - mu * mu + 1e-5f);
    const float2 gv = ((const float2*)g)[t];
    const float2 bv = ((const float2*)b)[t];
    const float y0 = (v.x - mu) * rs * gv.x + bv.x;
    const float y1 = (v.y - mu) * rs * gv.y + bv.y;
    union { short s2[2]; unsigned u; } o;
    o.s2[0] = f2bf(y0); o.s2[1] = f2bf(y1);
    ((unsigned*)out)[(long)row * 256 + t] = o.u;
}

// ---------------- spatial (window) MLP + residual ----------------
__global__ __launch_bounds__(256) void spatial_mlp(const short* __restrict__ xn,
                                                   const float* __restrict__ x,
                                                   const float* __restrict__ sw,
                                                   const float* __restrict__ sb,
                                                   float* x1) {
    const int head = blockIdx.y;
    const int t = threadIdx.x;
    const int ch = t & 31;
    const int wloc = t >> 5;
    const int win = blockIdx.x * 8 + wloc;        // 0..2591
    const int b = win / 81;
    const int rr = win - b * 81;
    const int wi = rr / 9;
    const int wj = rr - wi * 9;
    const int c = head * 32 + ch;

    float xv[49];
#pragma unroll
    for (int j = 0; j < 49; j++) {
        const int pr = wi * 7 + j / 7 - 4;        // padded row - P_T
        const int pc = wj * 7 + j % 7 - 4;        // padded col - P_L
        float v = 0.0f;
        if (pr >= 0 && pr < 56 && pc >= 0 && pc < 56)
            v = bf2f(xn[((long)((b * 56 + pr) * 56 + pc)) * 512 + c]);
        xv[j] = v;
    }

    const float* swh = sw + head * 2401;
    const float* sbh = sb + head * 49;

#pragma unroll 1
    for (int t7 = 0; t7 < 7; t7++) {
        float acc[7];
#pragma unroll
        for (int ii = 0; ii < 7; ii++) acc[ii] = sbh[t7 * 7 + ii];
#pragma unroll
        for (int ii = 0; ii < 7; ii++) {
            const float* swr = swh + (t7 * 7 + ii) * 49;
#pragma unroll
            for (int j = 0; j < 49; j++)
                acc[ii] = fmaf(swr[j], xv[j], acc[ii]);
        }
        const int pr = wi * 7 + t7 - 4;
        if (pr >= 0 && pr < 56) {
#pragma unroll
            for (int ii = 0; ii < 7; ii++) {
                const int pc = wj * 7 + ii - 4;
                if (pc >= 0 && pc < 56) {
                    const long idx = ((long)((b * 56 + pr) * 56 + pc)) * 512 + c;
                    x1[idx] = x[idx] + acc[ii];
                }
            }
        }
    }
}

// ------------- 256x128 8-wave deep-pipelined bf16 GEMM (8-phase style) -------
// A[M,K] row-major, Bw[N,K] row-major (B^T). BK=64. LDS ring-3 of
// (A 32KB + B 16KB) = 144 KB -> 1 block/CU, 8 waves (4M x 2N, 64x64 each).
// Per K-tile, 2 phases (kh=0/1), each:
//   {8x ds_read_b128; stage half-tile of t+2; s_barrier; lgkmcnt(0);
//    setprio(1); 16 MFMA; setprio(0); s_barrier}
// Counted vmcnt(6) once per K-tile (per-wave vmcnt THEN barrier => all waves'
// tile-(t+1) loads landed). Ring-3 => staging t+2 never touches a buffer
// readable by tiles t or t+1 (race-free by construction).
// Swizzle: 16B-chunk c3 ^= (row&7) on 128B rows; write side pre-swizzles the
// global source column (global_load_lds dest stays linear).
template <int K, int N, bool GELU>
__global__ __launch_bounds__(512, 2) void gemm256(const short* __restrict__ A,
                                                  const short* __restrict__ Bw,
                                                  const float* __restrict__ bias,
                                                  const float* res,
                                                  void* Cout) {
    __shared__ __attribute__((aligned(16))) short S[73728];  // 144 KB
    const int tid = threadIdx.x;
    const int lane = tid & 63;
    const int wid = tid >> 6;          // 0..7
    const int wm = wid >> 1;           // 0..3  M-strip (64 rows)
    const int wn = wid & 1;            // 0..1  N-strip (64 cols)
    const int lr = lane & 15;
    const int kg = (lane >> 4) & 3;

    // T1: bijective XCD-aware remap (nwg % 8 == 0)
    const int gx = gridDim.x;
    const int lin = blockIdx.y * gx + blockIdx.x;
    const int cpx = (gx * gridDim.y) >> 3;
    const int orig = (lin & 7) * cpx + (lin >> 3);
    const long mBase = (long)(orig / gx) * 256;
    const long nBase = (long)(orig % gx) * 128;

    // staging source (pre-swizzled column chunk; LDS dest linear)
    const int sRow = tid >> 3;                        // 0..63
    const int sChunk = (tid & 7) ^ ((tid >> 3) & 7);  // key = row&7
    const short* aS = A + (mBase + sRow) * K + sChunk * 8;
    const short* bS = Bw + (nBase + sRow) * K + sChunk * 8;

    auto stageA = [&](int t) {                        // 4 loads: A[256][64]
        const int r = t % 3;
        const long k0 = (long)t * 64;
        char* d = (char*)S + r * 32768 + tid * 16;
#pragma unroll
        for (int j = 0; j < 4; ++j)
            __builtin_amdgcn_global_load_lds(
                (const __attribute__((address_space(1))) void*)(aS + k0 + (long)j * 64 * K),
                (__attribute__((address_space(3))) void*)(d + j * 8192), 16, 0, 0);
    };
    auto stageB = [&](int t) {                        // 2 loads: B[128][64]
        const int r = t % 3;
        const long k0 = (long)t * 64;
        char* d = (char*)S + 98304 + r * 16384 + tid * 16;
#pragma unroll
        for (int j = 0; j < 2; ++j)
            __builtin_amdgcn_global_load_lds(
                (const __attribute__((address_space(1))) void*)(bS + k0 + (long)j * 64 * K),
                (__attribute__((address_space(3))) void*)(d + j * 8192), 16, 0, 0);
    };

    // fragment LDS byte offsets: row*128 + ((kh*4+kg)^(row&7))*16, row&7 = lr&7
    const int c0 = ((0 + kg) ^ (lr & 7)) * 16;        // kh=0 chunk
    const int c1 = ((4 + kg) ^ (lr & 7)) * 16;        // kh=1 chunk
    const int aRow0 = (wm * 64 + lr) * 128;           // + m*2048
    const int bRow0 = (wn * 64 + lr) * 128;           // + n*2048

    f32x4 acc[4][4] = {};

    stageA(0); stageB(0); stageA(1); stageB(1);       // 12 loads in flight
    asm volatile("s_waitcnt vmcnt(6)" ::: "memory");  // tile 0 landed
    __builtin_amdgcn_s_barrier();

    const int NT = K / 64;
    for (int t = 0; t < NT; ++t) {
        const char* Ab = (const char*)S + (t % 3) * 32768;
        const char* Bb = (const char*)S + 98304 + (t % 3) * 16384;
        bf16x8 af[4], bf[4];

        // ---- phase 0: kh = 0 ----
#pragma unroll
        for (int m = 0; m < 4; ++m) af[m] = *(const bf16x8*)(Ab + aRow0 + m * 2048 + c0);
#pragma unroll
        for (int n = 0; n < 4; ++n) bf[n] = *(const bf16x8*)(Bb + bRow0 + n * 2048 + c0);
        if (t + 2 < NT) stageA(t + 2);
        __builtin_amdgcn_s_barrier();
        asm volatile("s_waitcnt lgkmcnt(0)" ::: "memory");
        __builtin_amdgcn_s_setprio(1);
#pragma unroll
        for (int m = 0; m < 4; ++m)
#pragma unroll
            for (int n = 0; n < 4; ++n)
                acc[m][n] = __builtin_amdgcn_mfma_f32_16x16x32_bf16(bf[n], af[m],
                                                                    acc[m][n], 0, 0, 0);
        __builtin_amdgcn_s_setprio(0);
        __builtin_amdgcn_s_barrier();

        // ---- phase 1: kh = 1 ----
#pragma unroll
        for (int m = 0; m < 4; ++m) af[m] = *(const bf16x8*)(Ab + aRow0 + m * 2048 + c1);
#pragma unroll
        for (int n = 0; n < 4; ++n) bf[n] = *(const bf16x8*)(Bb + bRow0 + n * 2048 + c1);
        if (t + 2 < NT) stageB(t + 2);
        __builtin_amdgcn_s_barrier();
        asm volatile("s_waitcnt lgkmcnt(0)" ::: "memory");
        __builtin_amdgcn_s_setprio(1);
#pragma unroll
        for (int m = 0; m < 4; ++m)
#pragma unroll
            for (int n = 0; n < 4; ++n)
                acc[m][n] = __builtin_amdgcn_mfma_f32_16x16x32_bf16(bf[n], af[m],
                                                                    acc[m][n], 0, 0, 0);
        __builtin_amdgcn_s_setprio(0);
        // tile boundary: counted vmcnt BEFORE barrier (tile t+1 fully landed)
        if (t + 2 < NT)      asm volatile("s_waitcnt vmcnt(6)" ::: "memory");
        else if (t + 1 < NT) asm volatile("s_waitcnt vmcnt(0)" ::: "memory");
        __builtin_amdgcn_s_barrier();
    }

    // epilogue: operand-swapped fragment = C^T layout:
    //   C row  = mBase + wm*64 + m*16 + lr
    //   C cols = nBase + wn*64 + n*16 + kg*4 + (0..3)   (consecutive)
#pragma unroll
    for (int n = 0; n < 4; ++n) {
        const long col0 = nBase + wn * 64 + n * 16 + kg * 4;
        const f32x4 bv4 = *(const f32x4*)(bias + col0);
#pragma unroll
        for (int m = 0; m < 4; ++m) {
            const long row = mBase + wm * 64 + m * 16 + lr;
            const long idx = row * N + col0;
            if (GELU) {
                s16x4 o;
#pragma unroll
                for (int r = 0; r < 4; ++r)
                    o[r] = f2bf(gelu_fast(acc[m][n][r] + bv4[r]));
                *(s16x4*)((short*)Cout + idx) = o;
            } else {
                const f32x4 rv = *(const f32x4*)(res + idx);
                f32x4 o;
#pragma unroll
                for (int r = 0; r < 4; ++r) o[r] = acc[m][n][r] + bv4[r] + rv[r];
                *(f32x4*)((float*)Cout + idx) = o;
            }
        }
    }
}

extern "C" void kernel_launch(void* const* d_in, const int* in_sizes, int n_in,
                              void* d_out, int out_size, void* d_ws, size_t ws_size,
                              hipStream_t stream) {
    const float* x    = (const float*)d_in[0];
    const float* n1g  = (const float*)d_in[1];
    const float* n1b  = (const float*)d_in[2];
    const float* sw   = (const float*)d_in[3];
    const float* sb   = (const float*)d_in[4];
    const float* n2g  = (const float*)d_in[5];
    const float* n2b  = (const float*)d_in[6];
    const float* fc1w = (const float*)d_in[7];
    const float* fc1b = (const float*)d_in[8];
    const float* fc2w = (const float*)d_in[9];
    const float* fc2b = (const float*)d_in[10];
    float* out = (float*)d_out;

    // workspace layout (bytes)
    char* ws = (char*)d_ws;
    short* xn  = (short*)ws;                      // MM*512*2    = 102,760,448  (xn, then xn2)
    short* hb  = (short*)(ws + 102760448);        // MM*2048*2   = 411,041,792
    short* w1b = (short*)(ws + 513802240);        // 2048*512*2  =   2,097,152
    short* w2b = (short*)(ws + 515899392);        // 512*2048*2  =   2,097,152

    cvt_bf16<<<4096, 256, 0, stream>>>(fc1w, w1b, 2048 * 512);
    cvt_bf16<<<4096, 256, 0, stream>>>(fc2w, w2b, 512 * 2048);

    // LN1: x -> xn (bf16)
    ln512<<<MM, 256, 0, stream>>>(x, n1g, n1b, xn);

    // spatial MLP + residual: x1 = x + y  (into d_out)
    spatial_mlp<<<dim3(324, 16), 256, 0, stream>>>(xn, x, sw, sb, out);

    // LN2: x1 -> xn2 (bf16, reuse xn buffer)
    ln512<<<MM, 256, 0, stream>>>(out, n2g, n2b, xn);

    // FC1 + gelu -> h (bf16)   grid: 16 N-tiles x 392 M-tiles
    gemm256<512, 2048, true><<<dim3(16, 392), 512, 0, stream>>>(xn, w1b, fc1b, nullptr, hb);

    // FC2 + bias + residual -> out (f32, reads x1 from d_out in place)
    gemm256<2048, 512, false><<<dim3(4, 392), 512, 0, stream>>>(hb, w2b, fc2b, out, out);
}

// Round 7
// 1172.793 us; speedup vs baseline: 1.3145x; 1.0152x over previous
//
#include <hip/hip_runtime.h>

#define HH 56
#define WW 56
#define CC 512
#define BB 32
#define LL (HH*WW)
#define MM (BB*LL)     // 100352 tokens
#define HID 2048

typedef __attribute__((ext_vector_type(8))) __bf16 bf16x8;
typedef __attribute__((ext_vector_type(4))) float f32x4;
typedef __attribute__((ext_vector_type(4))) short s16x4;

__device__ __forceinline__ short f2bf(float f) {
    union { float f; unsigned u; } c; c.f = f;
    unsigned r = c.u + 0x7fffu + ((c.u >> 16) & 1u);   // round-to-nearest-even
    return (short)(r >> 16);
}
__device__ __forceinline__ float bf2f(short s) {
    union { unsigned u; float f; } c; c.u = ((unsigned)(unsigned short)s) << 16;
    return c.f;
}

// fast gelu: v * t/(t+1), t = e^{2*0.7978845608*(v+0.044715 v^3)}
__device__ __forceinline__ float gelu_fast(float v) {
    float xg = 0.7978845608f * (v + 0.044715f * v * v * v);
    xg = fminf(xg, 15.0f);
    float t = __expf(2.0f * xg);
    return v * (t / (t + 1.0f));
}

// ---------------- f32 -> bf16 weight conversion ----------------
__global__ __launch_bounds__(256) void cvt_bf16(const float* __restrict__ in,
                                                short* __restrict__ out, int n) {
    int i = blockIdx.x * 256 + threadIdx.x;
    if (i < n) out[i] = f2bf(in[i]);
}

// ---------------- LayerNorm over 512 channels, 1 row / block ----------------
__global__ __launch_bounds__(256) void ln512(const float* __restrict__ x,
                                             const float* __restrict__ g,
                                             const float* __restrict__ b,
                                             short* __restrict__ out) {
    const int row = blockIdx.x;
    const int t = threadIdx.x;
    const float2 v = ((const float2*)(x + (long)row * 512))[t];
    float s = v.x + v.y;
    float q = v.x * v.x + v.y * v.y;
#pragma unroll
    for (int off = 32; off > 0; off >>= 1) {
        s += __shfl_xor(s, off, 64);
        q += __shfl_xor(q, off, 64);
    }
    __shared__ float red[8];
    const int wv = t >> 6;
    if ((t & 63) == 0) { red[wv] = s; red[4 + wv] = q; }
    __syncthreads();
    s = red[0] + red[1] + red[2] + red[3];
    q = red[4] + red[5] + red[6] + red[7];
    const float mu = s * (1.0f / 512.0f);
    const float rs = rsqrtf(q * (1.0f / 512.0f) - mu * mu + 1e-5f);
    const float2 gv = ((const float2*)g)[t];
    const float2 bv = ((const float2*)b)[t];
    const float y0 = (v.x - mu) * rs * gv.x + bv.x;
    const float y1 = (v.y - mu) * rs * gv.y + bv.y;
    union { short s2[2]; unsigned u; } o;
    o.s2[0] = f2bf(y0); o.s2[1] = f2bf(y1);
    ((unsigned*)out)[(long)row * 256 + t] = o.u;
}

// ---------------- spatial (window) MLP + residual ----------------
__global__ __launch_bounds__(256) void spatial_mlp(const short* __restrict__ xn,
                                                   const float* __restrict__ x,
                                                   const float* __restrict__ sw,
                                                   const float* __restrict__ sb,
                                                   float* x1) {
    const int head = blockIdx.y;
    const int t = threadIdx.x;
    const int ch = t & 31;
    const int wloc = t >> 5;
    const int win = blockIdx.x * 8 + wloc;        // 0..2591
    const int b = win / 81;
    const int rr = win - b * 81;
    const int wi = rr / 9;
    const int wj = rr - wi * 9;
    const int c = head * 32 + ch;

    float xv[49];
#pragma unroll
    for (int j = 0; j < 49; j++) {
        const int pr = wi * 7 + j / 7 - 4;        // padded row - P_T
        const int pc = wj * 7 + j % 7 - 4;        // padded col - P_L
        float v = 0.0f;
        if (pr >= 0 && pr < 56 && pc >= 0 && pc < 56)
            v = bf2f(xn[((long)((b * 56 + pr) * 56 + pc)) * 512 + c]);
        xv[j] = v;
    }

    const float* swh = sw + head * 2401;
    const float* sbh = sb + head * 49;

#pragma unroll 1
    for (int t7 = 0; t7 < 7; t7++) {
        float acc[7];
#pragma unroll
        for (int ii = 0; ii < 7; ii++) acc[ii] = sbh[t7 * 7 + ii];
#pragma unroll
        for (int ii = 0; ii < 7; ii++) {
            const float* swr = swh + (t7 * 7 + ii) * 49;
#pragma unroll
            for (int j = 0; j < 49; j++)
                acc[ii] = fmaf(swr[j], xv[j], acc[ii]);
        }
        const int pr = wi * 7 + t7 - 4;
        if (pr >= 0 && pr < 56) {
#pragma unroll
            for (int ii = 0; ii < 7; ii++) {
                const int pc = wj * 7 + ii - 4;
                if (pc >= 0 && pc < 56) {
                    const long idx = ((long)((b * 56 + pr) * 56 + pc)) * 512 + c;
                    x1[idx] = x[idx] + acc[ii];
                }
            }
        }
    }
}

// ------------- 256x128 8-wave deep-pipelined bf16 GEMM, ring-3 ---------------
// IDENTICAL schedule/geometry to round 6 EXCEPT: the K-loop is manually
// 3-unrolled so every LDS ring-buffer index is a COMPILE-TIME literal.
// Hypothesis under test: runtime (t%3) indexing prevented alias analysis from
// proving staged-buffer != read-buffer, forcing a hidden s_waitcnt vmcnt(0)
// before each phase's ds_reads (full HBM latency exposed per phase).
// With literal indices the compiler can prove disjointness and the counted
// vmcnt(6) pipeline actually stays in flight.
template <int K, int N, bool GELU>
__global__ __launch_bounds__(512, 2) void gemm256(const short* __restrict__ A,
                                                  const short* __restrict__ Bw,
                                                  const float* __restrict__ bias,
                                                  const float* res,
                                                  void* Cout) {
    __shared__ __attribute__((aligned(16))) short S[73728];  // 144 KB
    const int tid = threadIdx.x;
    const int lane = tid & 63;
    const int wid = tid >> 6;          // 0..7
    const int wm = wid >> 1;           // 0..3  M-strip (64 rows)
    const int wn = wid & 1;            // 0..1  N-strip (64 cols)
    const int lr = lane & 15;
    const int kg = (lane >> 4) & 3;

    // T1: bijective XCD-aware remap (nwg % 8 == 0)
    const int gx = gridDim.x;
    const int lin = blockIdx.y * gx + blockIdx.x;
    const int cpx = (gx * gridDim.y) >> 3;
    const int orig = (lin & 7) * cpx + (lin >> 3);
    const long mBase = (long)(orig / gx) * 256;
    const long nBase = (long)(orig % gx) * 128;

    // staging source (pre-swizzled column chunk; LDS dest linear)
    const int sRow = tid >> 3;                        // 0..63
    const int sChunk = (tid & 7) ^ ((tid >> 3) & 7);  // key = row&7
    const short* aS = A + (mBase + sRow) * K + sChunk * 8;
    const short* bS = Bw + (nBase + sRow) * K + sChunk * 8;

    // r MUST be a compile-time literal at every call site (alias proof).
    auto stageA = [&](int r, int t) {                 // 4 loads: A[256][64]
        const long k0 = (long)t * 64;
        char* d = (char*)S + r * 32768 + tid * 16;
#pragma unroll
        for (int j = 0; j < 4; ++j)
            __builtin_amdgcn_global_load_lds(
                (const __attribute__((address_space(1))) void*)(aS + k0 + (long)j * 64 * K),
                (__attribute__((address_space(3))) void*)(d + j * 8192), 16, 0, 0);
    };
    auto stageB = [&](int r, int t) {                 // 2 loads: B[128][64]
        const long k0 = (long)t * 64;
        char* d = (char*)S + 98304 + r * 16384 + tid * 16;
#pragma unroll
        for (int j = 0; j < 2; ++j)
            __builtin_amdgcn_global_load_lds(
                (const __attribute__((address_space(1))) void*)(bS + k0 + (long)j * 64 * K),
                (__attribute__((address_space(3))) void*)(d + j * 8192), 16, 0, 0);
    };

    // fragment LDS byte offsets: row*128 + ((kh*4+kg)^(row&7))*16, row&7 = lr&7
    const int c0 = ((0 + kg) ^ (lr & 7)) * 16;        // kh=0 chunk
    const int c1 = ((4 + kg) ^ (lr & 7)) * 16;        // kh=1 chunk
    const int aRow0 = (wm * 64 + lr) * 128;           // + m*2048
    const int bRow0 = (wn * 64 + lr) * 128;           // + n*2048

    f32x4 acc[4][4] = {};
    const int NT = K / 64;

// one K-tile: read buffer BUF (literal), stage tile T+2 into SBUF (literal)
#define GTILE(BUF, SBUF, T)                                                     \
    {                                                                           \
        const char* Ab = (const char*)S + (BUF) * 32768;                        \
        const char* Bb = (const char*)S + 98304 + (BUF) * 16384;                \
        bf16x8 af[4], bfv[4];                                                   \
        _Pragma("unroll")                                                       \
        for (int m = 0; m < 4; ++m) af[m] = *(const bf16x8*)(Ab + aRow0 + m * 2048 + c0); \
        _Pragma("unroll")                                                       \
        for (int n = 0; n < 4; ++n) bfv[n] = *(const bf16x8*)(Bb + bRow0 + n * 2048 + c0); \
        if ((T) + 2 < NT) stageA(SBUF, (T) + 2);                                \
        __builtin_amdgcn_s_barrier();                                           \
        asm volatile("s_waitcnt lgkmcnt(0)" ::: "memory");                      \
        __builtin_amdgcn_s_setprio(1);                                          \
        _Pragma("unroll")                                                       \
        for (int m = 0; m < 4; ++m)                                             \
            _Pragma("unroll")                                                   \
            for (int n = 0; n < 4; ++n)                                         \
                acc[m][n] = __builtin_amdgcn_mfma_f32_16x16x32_bf16(bfv[n], af[m], acc[m][n], 0, 0, 0); \
        __builtin_amdgcn_s_setprio(0);                                          \
        __builtin_amdgcn_s_barrier();                                           \
        _Pragma("unroll")                                                       \
        for (int m = 0; m < 4; ++m) af[m] = *(const bf16x8*)(Ab + aRow0 + m * 2048 + c1); \
        _Pragma("unroll")                                                       \
        for (int n = 0; n < 4; ++n) bfv[n] = *(const bf16x8*)(Bb + bRow0 + n * 2048 + c1); \
        if ((T) + 2 < NT) stageB(SBUF, (T) + 2);                                \
        __builtin_amdgcn_s_barrier();                                           \
        asm volatile("s_waitcnt lgkmcnt(0)" ::: "memory");                      \
        __builtin_amdgcn_s_setprio(1);                                          \
        _Pragma("unroll")                                                       \
        for (int m = 0; m < 4; ++m)                                             \
            _Pragma("unroll")                                                   \
            for (int n = 0; n < 4; ++n)                                         \
                acc[m][n] = __builtin_amdgcn_mfma_f32_16x16x32_bf16(bfv[n], af[m], acc[m][n], 0, 0, 0); \
        __builtin_amdgcn_s_setprio(0);                                          \
        if ((T) + 2 < NT)      asm volatile("s_waitcnt vmcnt(6)" ::: "memory"); \
        else if ((T) + 1 < NT) asm volatile("s_waitcnt vmcnt(0)" ::: "memory"); \
        __builtin_amdgcn_s_barrier();                                           \
    }

    stageA(0, 0); stageB(0, 0); stageA(1, 1); stageB(1, 1);   // 12 loads
    asm volatile("s_waitcnt vmcnt(6)" ::: "memory");          // tile 0 landed
    __builtin_amdgcn_s_barrier();

    int t = 0;
    for (; t + 3 <= NT; t += 3) {       // NT = 8 or 32, both == 2 (mod 3)
        GTILE(0, 2, t);
        GTILE(1, 0, t + 1);
        GTILE(2, 1, t + 2);
    }
    if (t < NT)     GTILE(0, 2, t);
    if (t + 1 < NT) GTILE(1, 0, t + 1);
#undef GTILE

    // epilogue: operand-swapped fragment = C^T layout:
    //   C row  = mBase + wm*64 + m*16 + lr
    //   C cols = nBase + wn*64 + n*16 + kg*4 + (0..3)   (consecutive)
#pragma unroll
    for (int n = 0; n < 4; ++n) {
        const long col0 = nBase + wn * 64 + n * 16 + kg * 4;
        const f32x4 bv4 = *(const f32x4*)(bias + col0);
#pragma unroll
        for (int m = 0; m < 4; ++m) {
            const long row = mBase + wm * 64 + m * 16 + lr;
            const long idx = row * N + col0;
            if (GELU) {
                s16x4 o;
#pragma unroll
                for (int r = 0; r < 4; ++r)
                    o[r] = f2bf(gelu_fast(acc[m][n][r] + bv4[r]));
                *(s16x4*)((short*)Cout + idx) = o;
            } else {
                const f32x4 rv = *(const f32x4*)(res + idx);
                f32x4 o;
#pragma unroll
                for (int r = 0; r < 4; ++r) o[r] = acc[m][n][r] + bv4[r] + rv[r];
                *(f32x4*)((float*)Cout + idx) = o;
            }
        }
    }
}

extern "C" void kernel_launch(void* const* d_in, const int* in_sizes, int n_in,
                              void* d_out, int out_size, void* d_ws, size_t ws_size,
                              hipStream_t stream) {
    const float* x    = (const float*)d_in[0];
    const float* n1g  = (const float*)d_in[1];
    const float* n1b  = (const float*)d_in[2];
    const float* sw   = (const float*)d_in[3];
    const float* sb   = (const float*)d_in[4];
    const float* n2g  = (const float*)d_in[5];
    const float* n2b  = (const float*)d_in[6];
    const float* fc1w = (const float*)d_in[7];
    const float* fc1b = (const float*)d_in[8];
    const float* fc2w = (const float*)d_in[9];
    const float* fc2b = (const float*)d_in[10];
    float* out = (float*)d_out;

    // workspace layout (bytes)
    char* ws = (char*)d_ws;
    short* xn  = (short*)ws;                      // MM*512*2    = 102,760,448  (xn, then xn2)
    short* hb  = (short*)(ws + 102760448);        // MM*2048*2   = 411,041,792
    short* w1b = (short*)(ws + 513802240);        // 2048*512*2  =   2,097,152
    short* w2b = (short*)(ws + 515899392);        // 512*2048*2  =   2,097,152

    cvt_bf16<<<4096, 256, 0, stream>>>(fc1w, w1b, 2048 * 512);
    cvt_bf16<<<4096, 256, 0, stream>>>(fc2w, w2b, 512 * 2048);

    // LN1: x -> xn (bf16)
    ln512<<<MM, 256, 0, stream>>>(x, n1g, n1b, xn);

    // spatial MLP + residual: x1 = x + y  (into d_out)
    spatial_mlp<<<dim3(324, 16), 256, 0, stream>>>(xn, x, sw, sb, out);

    // LN2: x1 -> xn2 (bf16, reuse xn buffer)
    ln512<<<MM, 256, 0, stream>>>(out, n2g, n2b, xn);

    // FC1 + gelu -> h (bf16)   grid: 16 N-tiles x 392 M-tiles
    gemm256<512, 2048, true><<<dim3(16, 392), 512, 0, stream>>>(xn, w1b, fc1b, nullptr, hb);

    // FC2 + bias + residual -> out (f32, reads x1 from d_out in place)
    gemm256<2048, 512, false><<<dim3(4, 392), 512, 0, stream>>>(hb, w2b, fc2b, out, out);
}